// Round 1
// baseline (1163.510 us; speedup 1.0000x reference)
//
#include <hip/hip_runtime.h>
#include <hip/hip_bf16.h>

// 2-layer LSTM (H=20) + FC(20->1), B=4096, T=512, D_in=1.
// Mapping: 1 wave (64 lanes) per block; 3 batch elements per wave.
// Lanes [20g, 20g+19] form group g handling batch b = 3*blockIdx + g.
// Lane j inside a group owns hidden unit j: it computes gate rows
// j, 20+j, 40+j, 60+j (i,f,g,o) as fully-local dot products. Weights are
// lane-private in VGPRs (weight-stationary). New h vectors are exchanged
// through LDS once per layer per step (write 1 float, read back 5x float4).

namespace {
constexpr int H_   = 20;
constexpr int T_   = 512;
constexpr int B_   = 4096;
constexpr int GPW  = 3;   // batch elements (groups) per wave

__device__ __forceinline__ float sigm(float v) {
    return 1.0f / (1.0f + __expf(-v));
}
__device__ __forceinline__ float tanh_fast(float v) {
    // tanh(v) = 1 - 2/(1+e^{2v}); saturates correctly for large |v|
    return 1.0f - 2.0f / (1.0f + __expf(2.0f * v));
}
} // namespace

__global__ __launch_bounds__(64, 1) void lstm2_fc_kernel(
    const float* __restrict__ x,
    const float* __restrict__ Wih0, const float* __restrict__ Whh0,
    const float* __restrict__ bih0, const float* __restrict__ bhh0,
    const float* __restrict__ Wih1, const float* __restrict__ Whh1,
    const float* __restrict__ bih1, const float* __restrict__ bhh1,
    const float* __restrict__ fcW,  const float* __restrict__ fcb,
    float* __restrict__ out)
{
    const int lane = threadIdx.x;            // 0..63
    const int g    = lane / H_;              // group 0..2 active, 3 idle
    const int j    = lane - g * H_;          // hidden unit 0..19
    const int b    = blockIdx.x * GPW + g;
    const bool st  = (g < GPW) && (b < B_);
    const int  bl  = (b < B_) ? b : (B_ - 1);

    __shared__ __align__(16) float h0s[4][H_];  // row 3 = pad for idle lanes
    __shared__ __align__(16) float h1s[4][H_];

    // ---- lane-private weights (VGPR-resident; all indices compile-time) ----
    float w0x[4], bias0[4], bias1[4];
    float w0h[4][H_], w1i[4][H_], w1h[4][H_];
    #pragma unroll
    for (int q = 0; q < 4; ++q) {
        const int r = q * H_ + j;            // torch gate-row order i,f,g,o
        w0x[q]   = Wih0[r];                  // Wih0 is [80,1]
        bias0[q] = bih0[r] + bhh0[r];
        bias1[q] = bih1[r] + bhh1[r];
        #pragma unroll
        for (int k = 0; k < H_; ++k) {
            w0h[q][k] = Whh0[r * H_ + k];
            w1i[q][k] = Wih1[r * H_ + k];
            w1h[q][k] = Whh1[r * H_ + k];
        }
    }

    // ---- state ----
    float h0r[H_], h1r[H_];
    #pragma unroll
    for (int k = 0; k < H_; ++k) { h0r[k] = 0.0f; h1r[k] = 0.0f; }
    float c0 = 0.0f, c1 = 0.0f;

    const float* xb = x + (size_t)bl * T_;
    float xv = xb[0];

    #pragma unroll 1
    for (int t = 0; t < T_; ++t) {
        // ================= layer 0 =================
        float g0[4];
        #pragma unroll
        for (int q = 0; q < 4; ++q) g0[q] = bias0[q] + w0x[q] * xv;
        #pragma unroll
        for (int k = 0; k < H_; ++k) {
            #pragma unroll
            for (int q = 0; q < 4; ++q) g0[q] += w0h[q][k] * h0r[k];
        }
        const float i0 = sigm(g0[0]);
        const float f0 = sigm(g0[1]);
        const float z0 = tanh_fast(g0[2]);
        const float o0 = sigm(g0[3]);
        c0 = f0 * c0 + i0 * z0;
        const float h0n = o0 * tanh_fast(c0);

        if (g < GPW) h0s[g][j] = h0n;
        __syncthreads();

        // prefetch next x while LDS settles / before the long FMA chain
        const int tn = (t + 1 < T_) ? (t + 1) : (T_ - 1);
        xv = xb[tn];

        #pragma unroll
        for (int c4 = 0; c4 < 5; ++c4) {
            const float4 v = *reinterpret_cast<const float4*>(&h0s[g][c4 * 4]);
            h0r[c4 * 4 + 0] = v.x; h0r[c4 * 4 + 1] = v.y;
            h0r[c4 * 4 + 2] = v.z; h0r[c4 * 4 + 3] = v.w;
        }

        // ================= layer 1 =================
        float g1[4];
        #pragma unroll
        for (int q = 0; q < 4; ++q) g1[q] = bias1[q];
        #pragma unroll
        for (int k = 0; k < H_; ++k) {
            #pragma unroll
            for (int q = 0; q < 4; ++q) g1[q] += w1i[q][k] * h0r[k];
        }
        #pragma unroll
        for (int k = 0; k < H_; ++k) {
            #pragma unroll
            for (int q = 0; q < 4; ++q) g1[q] += w1h[q][k] * h1r[k];
        }
        const float i1 = sigm(g1[0]);
        const float f1 = sigm(g1[1]);
        const float z1 = tanh_fast(g1[2]);
        const float o1 = sigm(g1[3]);
        c1 = f1 * c1 + i1 * z1;
        const float h1n = o1 * tanh_fast(c1);

        if (g < GPW) h1s[g][j] = h1n;
        __syncthreads();

        #pragma unroll
        for (int c4 = 0; c4 < 5; ++c4) {
            const float4 v = *reinterpret_cast<const float4*>(&h1s[g][c4 * 4]);
            h1r[c4 * 4 + 0] = v.x; h1r[c4 * 4 + 1] = v.y;
            h1r[c4 * 4 + 2] = v.z; h1r[c4 * 4 + 3] = v.w;
        }
    }

    // ================= FC epilogue =================
    if (st && j == 0) {
        float acc = fcb[0];
        #pragma unroll
        for (int k = 0; k < H_; ++k) acc += fcW[k] * h1r[k];
        out[b] = acc;
    }
}

extern "C" void kernel_launch(void* const* d_in, const int* in_sizes, int n_in,
                              void* d_out, int out_size, void* d_ws, size_t ws_size,
                              hipStream_t stream) {
    const float* x    = (const float*)d_in[0];
    const float* Wih0 = (const float*)d_in[1];
    const float* Whh0 = (const float*)d_in[2];
    const float* bih0 = (const float*)d_in[3];
    const float* bhh0 = (const float*)d_in[4];
    const float* Wih1 = (const float*)d_in[5];
    const float* Whh1 = (const float*)d_in[6];
    const float* bih1 = (const float*)d_in[7];
    const float* bhh1 = (const float*)d_in[8];
    const float* fcW  = (const float*)d_in[9];
    const float* fcb  = (const float*)d_in[10];
    float* out = (float*)d_out;

    const int grid = (B_ + GPW - 1) / GPW;   // 1366 blocks, 1 wave each
    lstm2_fc_kernel<<<dim3(grid), dim3(64), 0, stream>>>(
        x, Wih0, Whh0, bih0, bhh0, Wih1, Whh1, bih1, bhh1, fcW, fcb, out);
}

// Round 2
// 1011.382 us; speedup vs baseline: 1.1504x; 1.1504x over previous
//
#include <hip/hip_runtime.h>
#include <hip/hip_bf16.h>

// 2-layer LSTM (H=20) + FC(20->1), B=4096, T=512, D_in=1.
//
// Mapping: block = 128 threads = 2 waves, handling GPB=3 batch elements.
// Within each wave, lanes [20g, 20g+19] form group g (batch b = 3*blk + g);
// lane j owns hidden unit j. Gate-split across waves: wave 0 computes gate
// rows {i, f} (rows j, 20+j), wave 1 computes {g, o} (rows 40+j, 60+j).
// Per-lane weights: 2 gates x (Whh0 20 + Wih1 20 + Whh1 20) = 120 floats ->
// fits addressable VGPRs (v0..v255), unlike the 240-float version which the
// compiler silently spilled to AGPRs (v_accvgpr traffic ~2x VALU inflation).
//
// Activated gates are exchanged via LDS (2 floats/lane each way); c and h are
// recomputed redundantly in both waves from bitwise-identical exchanged
// values. h vectors broadcast via LDS rows padded to 24 floats (16B-aligned
// float4 broadcast reads). 4 two-wave barriers per timestep.

namespace {
constexpr int H_  = 20;
constexpr int T_  = 512;
constexpr int B_  = 4096;
constexpr int GPB = 3;    // batch elements (groups) per block

__device__ __forceinline__ float sigm(float v) {
    return 1.0f / (1.0f + __expf(-v));
}
__device__ __forceinline__ float tanh_fast(float v) {
    // tanh(v) = 1 - 2/(1+e^{2v}); saturates correctly for large |v|
    return 1.0f - 2.0f / (1.0f + __expf(2.0f * v));
}
} // namespace

__global__ __launch_bounds__(128, 2) void lstm2_fc_kernel(
    const float* __restrict__ x,
    const float* __restrict__ Wih0, const float* __restrict__ Whh0,
    const float* __restrict__ bih0, const float* __restrict__ bhh0,
    const float* __restrict__ Wih1, const float* __restrict__ Whh1,
    const float* __restrict__ bih1, const float* __restrict__ bhh1,
    const float* __restrict__ fcW,  const float* __restrict__ fcb,
    float* __restrict__ out)
{
    const int tid  = threadIdx.x;
    const int w    = tid >> 6;            // 0: gates {i,f}, 1: gates {g,o}
    const int lane = tid & 63;
    const int g    = lane / H_;           // group 0..2 active, 3 idle
    const int j    = lane - g * H_;       // hidden unit 0..19
    const int b    = blockIdx.x * GPB + g;
    const bool st  = (g < GPB) && (b < B_);
    const int  bl  = (b < B_) ? b : (B_ - 1);

    __shared__ float exch[2][2][64];                 // [wave][slot][lane]
    __shared__ __align__(16) float h0s[4][24];       // rows padded to 24
    __shared__ __align__(16) float h1s[4][24];

    // ---- lane-private weights (all indices compile-time) ----
    float w0x[2], bias0[2], bias1[2];
    float w0h[2][H_], w1i[2][H_], w1h[2][H_];
    #pragma unroll
    for (int q = 0; q < 2; ++q) {
        const int r = (2 * w + q) * H_ + j;          // torch order i,f,g,o
        w0x[q]   = Wih0[r];                          // Wih0 is [80,1]
        bias0[q] = bih0[r] + bhh0[r];
        bias1[q] = bih1[r] + bhh1[r];
        #pragma unroll
        for (int k = 0; k < H_; ++k) {
            w0h[q][k] = Whh0[r * H_ + k];
            w1i[q][k] = Wih1[r * H_ + k];
            w1h[q][k] = Whh1[r * H_ + k];
        }
    }

    // ---- state (replicated in both waves, kept bitwise-consistent) ----
    float h0r[H_], h1r[H_];
    #pragma unroll
    for (int k = 0; k < H_; ++k) { h0r[k] = 0.0f; h1r[k] = 0.0f; }
    float c0 = 0.0f, c1 = 0.0f;

    const float* xb = x + (size_t)bl * T_;
    float xv = xb[0];

    #pragma unroll 1
    for (int t = 0; t < T_; ++t) {
        // ================= layer 0: own 2 gate rows =================
        float g0[2];
        #pragma unroll
        for (int q = 0; q < 2; ++q) g0[q] = fmaf(w0x[q], xv, bias0[q]);
        #pragma unroll
        for (int k = 0; k < H_; ++k) {
            #pragma unroll
            for (int q = 0; q < 2; ++q) g0[q] = fmaf(w0h[q][k], h0r[k], g0[q]);
        }
        float a0, a1;
        if (w == 0) { a0 = sigm(g0[0]);      a1 = sigm(g0[1]); }
        else        { a0 = tanh_fast(g0[0]); a1 = sigm(g0[1]); }
        exch[w][0][lane] = a0;
        exch[w][1][lane] = a1;
        __syncthreads();                                   // BAR 1
        float i0, f0, z0, o0;
        if (w == 0) { i0 = a0; f0 = a1;
                      z0 = exch[1][0][lane]; o0 = exch[1][1][lane]; }
        else        { i0 = exch[0][0][lane]; f0 = exch[0][1][lane];
                      z0 = a0; o0 = a1; }
        c0 = f0 * c0 + i0 * z0;
        const float h0n = o0 * tanh_fast(c0);
        if (w == 0) h0s[g][j] = h0n;
        __syncthreads();                                   // BAR 2

        // prefetch next x while LDS settles
        const int tn = (t + 1 < T_) ? (t + 1) : (T_ - 1);
        xv = xb[tn];

        #pragma unroll
        for (int c4 = 0; c4 < 5; ++c4) {
            const float4 v = *reinterpret_cast<const float4*>(&h0s[g][c4 * 4]);
            h0r[c4 * 4 + 0] = v.x; h0r[c4 * 4 + 1] = v.y;
            h0r[c4 * 4 + 2] = v.z; h0r[c4 * 4 + 3] = v.w;
        }

        // ================= layer 1: own 2 gate rows =================
        float ai[2], ah[2];                      // 4 independent FMA chains
        #pragma unroll
        for (int q = 0; q < 2; ++q) { ai[q] = bias1[q]; ah[q] = 0.0f; }
        #pragma unroll
        for (int k = 0; k < H_; ++k) {
            #pragma unroll
            for (int q = 0; q < 2; ++q) {
                ai[q] = fmaf(w1i[q][k], h0r[k], ai[q]);
                ah[q] = fmaf(w1h[q][k], h1r[k], ah[q]);
            }
        }
        float g1[2];
        #pragma unroll
        for (int q = 0; q < 2; ++q) g1[q] = ai[q] + ah[q];

        float b0a, b1a;
        if (w == 0) { b0a = sigm(g1[0]);      b1a = sigm(g1[1]); }
        else        { b0a = tanh_fast(g1[0]); b1a = sigm(g1[1]); }
        exch[w][0][lane] = b0a;
        exch[w][1][lane] = b1a;
        __syncthreads();                                   // BAR 3
        float i1, f1, z1, o1;
        if (w == 0) { i1 = b0a; f1 = b1a;
                      z1 = exch[1][0][lane]; o1 = exch[1][1][lane]; }
        else        { i1 = exch[0][0][lane]; f1 = exch[0][1][lane];
                      z1 = b0a; o1 = b1a; }
        c1 = f1 * c1 + i1 * z1;
        const float h1n = o1 * tanh_fast(c1);
        if (w == 0) h1s[g][j] = h1n;
        __syncthreads();                                   // BAR 4

        #pragma unroll
        for (int c4 = 0; c4 < 5; ++c4) {
            const float4 v = *reinterpret_cast<const float4*>(&h1s[g][c4 * 4]);
            h1r[c4 * 4 + 0] = v.x; h1r[c4 * 4 + 1] = v.y;
            h1r[c4 * 4 + 2] = v.z; h1r[c4 * 4 + 3] = v.w;
        }
    }

    // ================= FC epilogue =================
    if (w == 0 && st && j == 0) {
        float acc = fcb[0];
        #pragma unroll
        for (int k = 0; k < H_; ++k) acc = fmaf(fcW[k], h1r[k], acc);
        out[b] = acc;
    }
}

extern "C" void kernel_launch(void* const* d_in, const int* in_sizes, int n_in,
                              void* d_out, int out_size, void* d_ws, size_t ws_size,
                              hipStream_t stream) {
    const float* x    = (const float*)d_in[0];
    const float* Wih0 = (const float*)d_in[1];
    const float* Whh0 = (const float*)d_in[2];
    const float* bih0 = (const float*)d_in[3];
    const float* bhh0 = (const float*)d_in[4];
    const float* Wih1 = (const float*)d_in[5];
    const float* Whh1 = (const float*)d_in[6];
    const float* bih1 = (const float*)d_in[7];
    const float* bhh1 = (const float*)d_in[8];
    const float* fcW  = (const float*)d_in[9];
    const float* fcb  = (const float*)d_in[10];
    float* out = (float*)d_out;

    const int grid = (B_ + GPB - 1) / GPB;   // 1366 blocks x 2 waves
    lstm2_fc_kernel<<<dim3(grid), dim3(128), 0, stream>>>(
        x, Wih0, Whh0, bih0, bhh0, Wih1, Whh1, bih1, bhh1, fcW, fcb, out);
}

// Round 3
// 997.817 us; speedup vs baseline: 1.1661x; 1.0136x over previous
//
#include <hip/hip_runtime.h>
#include <hip/hip_bf16.h>

// 2-layer LSTM (H=20) + FC(20->1), B=4096, T=512, D_in=1.
//
// Mapping: block = 128 threads = 2 waves, handling GPB=3 batch elements.
// Within each wave, lanes [20g, 20g+19] form group g (batch b = 3*blk + g);
// lane j owns hidden unit j. Gate-split across waves: wave 0 computes gate
// rows {i, f} (rows j, 20+j), wave 1 computes {g, o} (rows 40+j, 60+j).
//
// Round-3 change: round 2 showed VGPR_Count=96 < the 120 weight floats ->
// the compiler REMATERIALIZED weight loads every timestep (~120 global_loads
// + address VALU per wave per step; ~2.5x instruction inflation, VALUBusy
// pinned ~52%). Fix: pin every weight through an empty asm ("+v") after the
// one-time load, making the values opaque so remat is impossible and they
// stay VGPR-resident across the t-loop. ~190 live + temps fits the 256-reg
// cap from __launch_bounds__(128,2).

namespace {
constexpr int H_  = 20;
constexpr int T_  = 512;
constexpr int B_  = 4096;
constexpr int GPB = 3;    // batch elements (groups) per block

__device__ __forceinline__ float sigm(float v) {
    return 1.0f / (1.0f + __expf(-v));
}
__device__ __forceinline__ float tanh_fast(float v) {
    // tanh(v) = 1 - 2/(1+e^{2v}); saturates correctly for large |v|
    return 1.0f - 2.0f / (1.0f + __expf(2.0f * v));
}
} // namespace

__global__ __launch_bounds__(128, 2) void lstm2_fc_kernel(
    const float* __restrict__ x,
    const float* __restrict__ Wih0, const float* __restrict__ Whh0,
    const float* __restrict__ bih0, const float* __restrict__ bhh0,
    const float* __restrict__ Wih1, const float* __restrict__ Whh1,
    const float* __restrict__ bih1, const float* __restrict__ bhh1,
    const float* __restrict__ fcW,  const float* __restrict__ fcb,
    float* __restrict__ out)
{
    const int tid  = threadIdx.x;
    const int w    = tid >> 6;            // 0: gates {i,f}, 1: gates {g,o}
    const int lane = tid & 63;
    const int g    = lane / H_;           // group 0..2 active, 3 idle
    const int j    = lane - g * H_;       // hidden unit 0..19
    const int b    = blockIdx.x * GPB + g;
    const bool st  = (g < GPB) && (b < B_);
    const int  bl  = (b < B_) ? b : (B_ - 1);

    __shared__ float exch[2][2][64];                 // [wave][slot][lane]
    __shared__ __align__(16) float h0s[4][24];       // rows padded to 24
    __shared__ __align__(16) float h1s[4][24];

    // ---- lane-private weights (all indices compile-time) ----
    float w0x[2], bias0[2], bias1[2];
    float w0h[2][H_], w1i[2][H_], w1h[2][H_];
    #pragma unroll
    for (int q = 0; q < 2; ++q) {
        const int r = (2 * w + q) * H_ + j;          // torch order i,f,g,o
        w0x[q]   = Wih0[r];                          // Wih0 is [80,1]
        bias0[q] = bih0[r] + bhh0[r];
        bias1[q] = bih1[r] + bhh1[r];
        #pragma unroll
        for (int k = 0; k < H_; ++k) {
            w0h[q][k] = Whh0[r * H_ + k];
            w1i[q][k] = Wih1[r * H_ + k];
            w1h[q][k] = Whh1[r * H_ + k];
        }
    }

    // ---- pin weights in VGPRs: values become opaque -> no remat, no
    //      per-step reloads. (Round-2 counter evidence: VGPR=96 + ~2.5x
    //      VALU inflation from in-loop global_load rematerialization.)
    #pragma unroll
    for (int q = 0; q < 2; ++q) {
        asm volatile("" : "+v"(w0x[q]), "+v"(bias0[q]), "+v"(bias1[q]));
        #pragma unroll
        for (int k = 0; k < H_; ++k) {
            asm volatile("" : "+v"(w0h[q][k]), "+v"(w1i[q][k]), "+v"(w1h[q][k]));
        }
    }

    // ---- state (replicated in both waves, kept bitwise-consistent) ----
    float h0r[H_], h1r[H_];
    #pragma unroll
    for (int k = 0; k < H_; ++k) { h0r[k] = 0.0f; h1r[k] = 0.0f; }
    float c0 = 0.0f, c1 = 0.0f;

    const float* xb = x + (size_t)bl * T_;
    float xv = xb[0];

    #pragma unroll 1
    for (int t = 0; t < T_; ++t) {
        // ================= layer 0: own 2 gate rows =================
        float g0[2];
        #pragma unroll
        for (int q = 0; q < 2; ++q) g0[q] = fmaf(w0x[q], xv, bias0[q]);
        #pragma unroll
        for (int k = 0; k < H_; ++k) {
            #pragma unroll
            for (int q = 0; q < 2; ++q) g0[q] = fmaf(w0h[q][k], h0r[k], g0[q]);
        }
        float a0, a1;
        if (w == 0) { a0 = sigm(g0[0]);      a1 = sigm(g0[1]); }
        else        { a0 = tanh_fast(g0[0]); a1 = sigm(g0[1]); }
        exch[w][0][lane] = a0;
        exch[w][1][lane] = a1;
        __syncthreads();                                   // BAR 1
        float i0, f0, z0, o0;
        if (w == 0) { i0 = a0; f0 = a1;
                      z0 = exch[1][0][lane]; o0 = exch[1][1][lane]; }
        else        { i0 = exch[0][0][lane]; f0 = exch[0][1][lane];
                      z0 = a0; o0 = a1; }
        c0 = f0 * c0 + i0 * z0;
        const float h0n = o0 * tanh_fast(c0);
        if (w == 0) h0s[g][j] = h0n;
        __syncthreads();                                   // BAR 2

        // prefetch next x while LDS settles
        const int tn = (t + 1 < T_) ? (t + 1) : (T_ - 1);
        xv = xb[tn];

        #pragma unroll
        for (int c4 = 0; c4 < 5; ++c4) {
            const float4 v = *reinterpret_cast<const float4*>(&h0s[g][c4 * 4]);
            h0r[c4 * 4 + 0] = v.x; h0r[c4 * 4 + 1] = v.y;
            h0r[c4 * 4 + 2] = v.z; h0r[c4 * 4 + 3] = v.w;
        }

        // ================= layer 1: own 2 gate rows =================
        float ai[2], ah[2];                      // 4 independent FMA chains
        #pragma unroll
        for (int q = 0; q < 2; ++q) { ai[q] = bias1[q]; ah[q] = 0.0f; }
        #pragma unroll
        for (int k = 0; k < H_; ++k) {
            #pragma unroll
            for (int q = 0; q < 2; ++q) {
                ai[q] = fmaf(w1i[q][k], h0r[k], ai[q]);
                ah[q] = fmaf(w1h[q][k], h1r[k], ah[q]);
            }
        }
        float g1[2];
        #pragma unroll
        for (int q = 0; q < 2; ++q) g1[q] = ai[q] + ah[q];

        float b0a, b1a;
        if (w == 0) { b0a = sigm(g1[0]);      b1a = sigm(g1[1]); }
        else        { b0a = tanh_fast(g1[0]); b1a = sigm(g1[1]); }
        exch[w][0][lane] = b0a;
        exch[w][1][lane] = b1a;
        __syncthreads();                                   // BAR 3
        float i1, f1, z1, o1;
        if (w == 0) { i1 = b0a; f1 = b1a;
                      z1 = exch[1][0][lane]; o1 = exch[1][1][lane]; }
        else        { i1 = exch[0][0][lane]; f1 = exch[0][1][lane];
                      z1 = b0a; o1 = b1a; }
        c1 = f1 * c1 + i1 * z1;
        const float h1n = o1 * tanh_fast(c1);
        if (w == 0) h1s[g][j] = h1n;
        __syncthreads();                                   // BAR 4

        #pragma unroll
        for (int c4 = 0; c4 < 5; ++c4) {
            const float4 v = *reinterpret_cast<const float4*>(&h1s[g][c4 * 4]);
            h1r[c4 * 4 + 0] = v.x; h1r[c4 * 4 + 1] = v.y;
            h1r[c4 * 4 + 2] = v.z; h1r[c4 * 4 + 3] = v.w;
        }
    }

    // ================= FC epilogue =================
    if (w == 0 && st && j == 0) {
        float acc = fcb[0];
        #pragma unroll
        for (int k = 0; k < H_; ++k) acc = fmaf(fcW[k], h1r[k], acc);
        out[b] = acc;
    }
}

extern "C" void kernel_launch(void* const* d_in, const int* in_sizes, int n_in,
                              void* d_out, int out_size, void* d_ws, size_t ws_size,
                              hipStream_t stream) {
    const float* x    = (const float*)d_in[0];
    const float* Wih0 = (const float*)d_in[1];
    const float* Whh0 = (const float*)d_in[2];
    const float* bih0 = (const float*)d_in[3];
    const float* bhh0 = (const float*)d_in[4];
    const float* Wih1 = (const float*)d_in[5];
    const float* Whh1 = (const float*)d_in[6];
    const float* bih1 = (const float*)d_in[7];
    const float* bhh1 = (const float*)d_in[8];
    const float* fcW  = (const float*)d_in[9];
    const float* fcb  = (const float*)d_in[10];
    float* out = (float*)d_out;

    const int grid = (B_ + GPB - 1) / GPB;   // 1366 blocks x 2 waves
    lstm2_fc_kernel<<<dim3(grid), dim3(128), 0, stream>>>(
        x, Wih0, Whh0, bih0, bhh0, Wih1, Whh1, bih1, bhh1, fcW, fcb, out);
}

// Round 4
// 850.864 us; speedup vs baseline: 1.3674x; 1.1727x over previous
//
#include <hip/hip_runtime.h>
#include <hip/hip_bf16.h>

// 2-layer LSTM (H=20) + FC(20->1), B=4096, T=512, D_in=1.
//
// Round-4 mapping: block = 256 threads = 4 waves, GPB=3 batch elements.
// Wave w owns gate w (torch order i,f,g,o). Within each wave, lanes
// [20g, 20g+19] form group g (batch b = 3*blk + g); lane j owns hidden
// unit j, i.e. gate row w*20+j. Per-lane weights: ONE row of each of
// Whh0/Wih1/Whh1 (60 floats) + Wih0 scalar + 2 fused biases = 63 floats,
// which genuinely fits arch VGPRs at the 128-reg cap of
// __launch_bounds__(256,4) -- rounds 2/3 (120 floats) were silently
// AGPR-parked (VGPR_Count=96, +~1 instr per weight use per step).
//
// Per step: (1) each wave computes its gate's dot + activation,
// exchanges 1 float/lane via LDS (barrier); (2) ALL waves redundantly
// compute c,h (bitwise-identical inputs -> identical results), write h to
// a WAVE-PRIVATE LDS row and read it back broadcast-style -- intra-wave
// in-order DS needs NO barrier. Only 2 barriers/step (the 2 exchanges).
// Single-buffered exchange is race-free: values are read (and consumed,
// forcing waitcnt) strictly between the exchange barrier and the next
// barrier, while the next overwrite is gated behind that next barrier.

namespace {
constexpr int H_  = 20;
constexpr int T_  = 512;
constexpr int B_  = 4096;
constexpr int GPB = 3;    // batch elements (groups) per block

__device__ __forceinline__ float sigm(float v) {
    return 1.0f / (1.0f + __expf(-v));
}
__device__ __forceinline__ float tanh_fast(float v) {
    // tanh(v) = 1 - 2/(1+e^{2v}); saturates correctly for large |v|
    return 1.0f - 2.0f / (1.0f + __expf(2.0f * v));
}
} // namespace

__global__ __launch_bounds__(256, 4) void lstm2_fc_kernel(
    const float* __restrict__ x,
    const float* __restrict__ Wih0, const float* __restrict__ Whh0,
    const float* __restrict__ bih0, const float* __restrict__ bhh0,
    const float* __restrict__ Wih1, const float* __restrict__ Whh1,
    const float* __restrict__ bih1, const float* __restrict__ bhh1,
    const float* __restrict__ fcW,  const float* __restrict__ fcb,
    float* __restrict__ out)
{
    const int tid  = threadIdx.x;
    const int w_s  = __builtin_amdgcn_readfirstlane(tid >> 6); // gate 0..3 (SGPR)
    const int lane = tid & 63;
    const int g    = lane / H_;           // group 0..2 active, 3 = pad
    const int j    = lane - g * H_;       // hidden unit 0..19
    const int b    = blockIdx.x * GPB + g;
    const bool st  = (g < GPB) && (b < B_);
    const int  bl  = (b < B_) ? b : (B_ - 1);

    __shared__ float act0[4][64];                    // [gate][lane]
    __shared__ float act1[4][64];
    __shared__ __align__(16) float h0s[4][4][24];    // [wave][group][unit pad24]
    __shared__ __align__(16) float h1s[4][4][24];

    // ---- lane-private weights: gate row r = w_s*20 + j ----
    const int r = w_s * H_ + j;
    float w0x   = Wih0[r];                           // Wih0 is [80,1]
    float bias0 = bih0[r] + bhh0[r];
    float bias1 = bih1[r] + bhh1[r];
    float w0h[H_], w1i[H_], w1h[H_];
    #pragma unroll
    for (int k = 0; k < H_; ++k) {
        w0h[k] = Whh0[r * H_ + k];
        w1i[k] = Wih1[r * H_ + k];
        w1h[k] = Whh1[r * H_ + k];
    }
    // pin: forbid in-loop reload/remat of the weight set
    asm volatile("" : "+v"(w0x), "+v"(bias0), "+v"(bias1));
    #pragma unroll
    for (int k = 0; k < H_; ++k) {
        asm volatile("" : "+v"(w0h[k]), "+v"(w1i[k]), "+v"(w1h[k]));
    }

    // ---- state (replicated across waves, bitwise-consistent) ----
    float h0r[H_], h1r[H_];
    #pragma unroll
    for (int k = 0; k < H_; ++k) { h0r[k] = 0.0f; h1r[k] = 0.0f; }
    float c0 = 0.0f, c1 = 0.0f;

    float* myAct0 = &act0[w_s][lane];
    float* myAct1 = &act1[w_s][lane];
    const float4* h0row = reinterpret_cast<const float4*>(&h0s[w_s][g][0]);
    const float4* h1row = reinterpret_cast<const float4*>(&h1s[w_s][g][0]);

    const float* xb = x + (size_t)bl * T_;
    float xv = xb[0];

    #pragma unroll 1
    for (int t = 0; t < T_; ++t) {
        // ============ layer 0: own gate row (21 MACs, 4 chains) ============
        float s0 = fmaf(w0x, xv, bias0);
        float s1 = 0.0f, s2 = 0.0f, s3 = 0.0f;
        #pragma unroll
        for (int k = 0; k < H_; k += 4) {
            s0 = fmaf(w0h[k + 0], h0r[k + 0], s0);
            s1 = fmaf(w0h[k + 1], h0r[k + 1], s1);
            s2 = fmaf(w0h[k + 2], h0r[k + 2], s2);
            s3 = fmaf(w0h[k + 3], h0r[k + 3], s3);
        }
        const float gate0 = (s0 + s1) + (s2 + s3);
        float a0;
        if (w_s == 2) a0 = tanh_fast(gate0); else a0 = sigm(gate0);
        *myAct0 = a0;
        __syncthreads();                                   // BAR 1
        const float i0 = act0[0][lane];
        const float f0 = act0[1][lane];
        const float z0 = act0[2][lane];
        const float o0 = act0[3][lane];
        c0 = fmaf(f0, c0, i0 * z0);
        const float h0n = o0 * tanh_fast(c0);
        h0s[w_s][g][j] = h0n;                              // wave-private row

        // prefetch next x (latency hidden under layer-1 math)
        const int tn = (t + 1 < T_) ? (t + 1) : (T_ - 1);
        const float xnext = xb[tn];

        // broadcast readback (intra-wave RAW, no barrier needed)
        #pragma unroll
        for (int c4 = 0; c4 < 5; ++c4) {
            const float4 v = h0row[c4];
            h0r[c4 * 4 + 0] = v.x; h0r[c4 * 4 + 1] = v.y;
            h0r[c4 * 4 + 2] = v.z; h0r[c4 * 4 + 3] = v.w;
        }

        // ============ layer 1: own gate row (40 MACs, 4 chains) ============
        float u0 = bias1, u1 = 0.0f, u2 = 0.0f, u3 = 0.0f;
        #pragma unroll
        for (int k = 0; k < H_; k += 2) {
            u0 = fmaf(w1i[k + 0], h0r[k + 0], u0);
            u1 = fmaf(w1i[k + 1], h0r[k + 1], u1);
            u2 = fmaf(w1h[k + 0], h1r[k + 0], u2);
            u3 = fmaf(w1h[k + 1], h1r[k + 1], u3);
        }
        const float gate1 = (u0 + u1) + (u2 + u3);
        float a1;
        if (w_s == 2) a1 = tanh_fast(gate1); else a1 = sigm(gate1);
        *myAct1 = a1;
        __syncthreads();                                   // BAR 2
        const float i1 = act1[0][lane];
        const float f1 = act1[1][lane];
        const float z1 = act1[2][lane];
        const float o1 = act1[3][lane];
        c1 = fmaf(f1, c1, i1 * z1);
        const float h1n = o1 * tanh_fast(c1);
        h1s[w_s][g][j] = h1n;                              // wave-private row

        #pragma unroll
        for (int c4 = 0; c4 < 5; ++c4) {
            const float4 v = h1row[c4];
            h1r[c4 * 4 + 0] = v.x; h1r[c4 * 4 + 1] = v.y;
            h1r[c4 * 4 + 2] = v.z; h1r[c4 * 4 + 3] = v.w;
        }

        xv = xnext;
    }

    // ================= FC epilogue =================
    if (w_s == 0 && st && j == 0) {
        float acc = fcb[0];
        #pragma unroll
        for (int k = 0; k < H_; ++k) acc = fmaf(fcW[k], h1r[k], acc);
        out[b] = acc;
    }
}

extern "C" void kernel_launch(void* const* d_in, const int* in_sizes, int n_in,
                              void* d_out, int out_size, void* d_ws, size_t ws_size,
                              hipStream_t stream) {
    const float* x    = (const float*)d_in[0];
    const float* Wih0 = (const float*)d_in[1];
    const float* Whh0 = (const float*)d_in[2];
    const float* bih0 = (const float*)d_in[3];
    const float* bhh0 = (const float*)d_in[4];
    const float* Wih1 = (const float*)d_in[5];
    const float* Whh1 = (const float*)d_in[6];
    const float* bih1 = (const float*)d_in[7];
    const float* bhh1 = (const float*)d_in[8];
    const float* fcW  = (const float*)d_in[9];
    const float* fcb  = (const float*)d_in[10];
    float* out = (float*)d_out;

    const int grid = (B_ + GPB - 1) / GPB;   // 1366 blocks x 4 waves
    lstm2_fc_kernel<<<dim3(grid), dim3(256), 0, stream>>>(
        x, Wih0, Whh0, bih0, bhh0, Wih1, Whh1, bih1, bhh1, fcW, fcb, out);
}

// Round 5
// 819.846 us; speedup vs baseline: 1.4192x; 1.0378x over previous
//
#include <hip/hip_runtime.h>
#include <hip/hip_bf16.h>

// 2-layer LSTM (H=20) + FC(20->1), B=4096, T=512, D_in=1.
//
// Mapping (round 4): block = 256 threads = 4 waves, GPB=3 batch elements.
// Wave w owns gate w (torch order i,f,g,o); lanes [20g,20g+19] = group g
// (batch b = 3*blk + g); lane j owns hidden unit j -> gate row w*20+j.
// Per-lane weights: one row each of Whh0/Wih1/Whh1 (60) + Wih0 scalar +
// 2 fused biases = 63 floats.
//
// Round-5 changes (round 4 showed VGPR_Count=64 with cap 128: allocator
// split 64 arch + 64 AGPR -> ~60 v_accvgpr_read per wave per step; VALU
// issue-bound at 85%):
//  1. __launch_bounds__(256,3): VGPR cap 168 > ~140 pressure -> weights
//     stay in arch VGPRs, no accvgpr traffic. Occupancy 2048/168 -> 12
//     waves/CU (>= round 4's 10.24).
//  2. x staged to LDS once (coalesced); per-step x read is one broadcast
//     ds_read_b32 (row padded +1 dword so the 3 group rows land on
//     different banks). Kills per-step global addressing + vmcnt.
//
// Per step: 2 barriers (one per layer's activation exchange). c,h computed
// redundantly in all 4 waves from bitwise-identical exchanged activations;
// h broadcast via WAVE-PRIVATE LDS rows (intra-wave RAW, no barrier).

namespace {
constexpr int H_  = 20;
constexpr int T_  = 512;
constexpr int B_  = 4096;
constexpr int GPB = 3;    // batch elements (groups) per block

__device__ __forceinline__ float sigm(float v) {
    return 1.0f / (1.0f + __expf(-v));
}
__device__ __forceinline__ float tanh_fast(float v) {
    // tanh(v) = 1 - 2/(1+e^{2v}); saturates correctly for large |v|
    return 1.0f - 2.0f / (1.0f + __expf(2.0f * v));
}
} // namespace

__global__ __launch_bounds__(256, 3) void lstm2_fc_kernel(
    const float* __restrict__ x,
    const float* __restrict__ Wih0, const float* __restrict__ Whh0,
    const float* __restrict__ bih0, const float* __restrict__ bhh0,
    const float* __restrict__ Wih1, const float* __restrict__ Whh1,
    const float* __restrict__ bih1, const float* __restrict__ bhh1,
    const float* __restrict__ fcW,  const float* __restrict__ fcb,
    float* __restrict__ out)
{
    const int tid  = threadIdx.x;
    const int w_s  = __builtin_amdgcn_readfirstlane(tid >> 6); // gate 0..3 (SGPR)
    const int lane = tid & 63;
    const int g    = lane / H_;           // group 0..2 active, 3 = pad
    const int j    = lane - g * H_;       // hidden unit 0..19
    const int b    = blockIdx.x * GPB + g;
    const bool st  = (g < GPB) && (b < B_);
    const int  gx  = (g < GPB) ? g : (GPB - 1);

    __shared__ float xs[GPB][T_ + 1];                // +1 dword: de-alias banks
    __shared__ float act0[4][64];                    // [gate][lane]
    __shared__ float act1[4][64];
    __shared__ __align__(16) float h0s[4][4][24];    // [wave][group][unit pad24]
    __shared__ __align__(16) float h1s[4][4][24];

    // ---- stage x rows for this block's 3 batch elements (coalesced) ----
    {
        const int base_b = blockIdx.x * GPB;
        for (int idx = tid; idx < GPB * T_; idx += 256) {
            const int gg  = idx >> 9;           // /512
            const int tt  = idx & (T_ - 1);     // %512
            int row = base_b + gg; if (row >= B_) row = B_ - 1;
            xs[gg][tt] = x[(size_t)row * T_ + tt];
        }
    }

    // ---- lane-private weights: gate row r = w_s*20 + j ----
    const int r = w_s * H_ + j;
    float w0x   = Wih0[r];                           // Wih0 is [80,1]
    float bias0 = bih0[r] + bhh0[r];
    float bias1 = bih1[r] + bhh1[r];
    float w0h[H_], w1i[H_], w1h[H_];
    #pragma unroll
    for (int k = 0; k < H_; ++k) {
        w0h[k] = Whh0[r * H_ + k];
        w1i[k] = Wih1[r * H_ + k];
        w1h[k] = Whh1[r * H_ + k];
    }
    // pin: forbid in-loop reload/remat of the weight set
    asm volatile("" : "+v"(w0x), "+v"(bias0), "+v"(bias1));
    #pragma unroll
    for (int k = 0; k < H_; ++k) {
        asm volatile("" : "+v"(w0h[k]), "+v"(w1i[k]), "+v"(w1h[k]));
    }

    // ---- state (replicated across waves, bitwise-consistent) ----
    float h0r[H_], h1r[H_];
    #pragma unroll
    for (int k = 0; k < H_; ++k) { h0r[k] = 0.0f; h1r[k] = 0.0f; }
    float c0 = 0.0f, c1 = 0.0f;

    float* myAct0 = &act0[w_s][lane];
    float* myAct1 = &act1[w_s][lane];
    const float4* h0row = reinterpret_cast<const float4*>(&h0s[w_s][g][0]);
    const float4* h1row = reinterpret_cast<const float4*>(&h1s[w_s][g][0]);
    const float*  xrow  = &xs[gx][0];

    __syncthreads();                                 // xs ready
    float xv = xrow[0];

    #pragma unroll 1
    for (int t = 0; t < T_; ++t) {
        // ============ layer 0: own gate row (21 MACs, 4 chains) ============
        float s0 = fmaf(w0x, xv, bias0);
        float s1 = 0.0f, s2 = 0.0f, s3 = 0.0f;
        #pragma unroll
        for (int k = 0; k < H_; k += 4) {
            s0 = fmaf(w0h[k + 0], h0r[k + 0], s0);
            s1 = fmaf(w0h[k + 1], h0r[k + 1], s1);
            s2 = fmaf(w0h[k + 2], h0r[k + 2], s2);
            s3 = fmaf(w0h[k + 3], h0r[k + 3], s3);
        }
        const float gate0 = (s0 + s1) + (s2 + s3);
        float a0;
        if (w_s == 2) a0 = tanh_fast(gate0); else a0 = sigm(gate0);
        *myAct0 = a0;
        const float xnext = xrow[t + 1];   // t=511 reads pad slot; never used
        __syncthreads();                                   // BAR 1
        const float i0 = act0[0][lane];
        const float f0 = act0[1][lane];
        const float z0 = act0[2][lane];
        const float o0 = act0[3][lane];
        c0 = fmaf(f0, c0, i0 * z0);
        const float h0n = o0 * tanh_fast(c0);
        h0s[w_s][g][j] = h0n;                              // wave-private row

        // broadcast readback (intra-wave RAW, no barrier needed)
        #pragma unroll
        for (int c4 = 0; c4 < 5; ++c4) {
            const float4 v = h0row[c4];
            h0r[c4 * 4 + 0] = v.x; h0r[c4 * 4 + 1] = v.y;
            h0r[c4 * 4 + 2] = v.z; h0r[c4 * 4 + 3] = v.w;
        }

        // ============ layer 1: own gate row (40 MACs, 4 chains) ============
        float u0 = bias1, u1 = 0.0f, u2 = 0.0f, u3 = 0.0f;
        #pragma unroll
        for (int k = 0; k < H_; k += 2) {
            u0 = fmaf(w1i[k + 0], h0r[k + 0], u0);
            u1 = fmaf(w1i[k + 1], h0r[k + 1], u1);
            u2 = fmaf(w1h[k + 0], h1r[k + 0], u2);
            u3 = fmaf(w1h[k + 1], h1r[k + 1], u3);
        }
        const float gate1 = (u0 + u1) + (u2 + u3);
        float a1;
        if (w_s == 2) a1 = tanh_fast(gate1); else a1 = sigm(gate1);
        *myAct1 = a1;
        __syncthreads();                                   // BAR 2
        const float i1 = act1[0][lane];
        const float f1 = act1[1][lane];
        const float z1 = act1[2][lane];
        const float o1 = act1[3][lane];
        c1 = fmaf(f1, c1, i1 * z1);
        const float h1n = o1 * tanh_fast(c1);
        h1s[w_s][g][j] = h1n;                              // wave-private row

        #pragma unroll
        for (int c4 = 0; c4 < 5; ++c4) {
            const float4 v = h1row[c4];
            h1r[c4 * 4 + 0] = v.x; h1r[c4 * 4 + 1] = v.y;
            h1r[c4 * 4 + 2] = v.z; h1r[c4 * 4 + 3] = v.w;
        }

        xv = xnext;
    }

    // ================= FC epilogue =================
    if (w_s == 0 && st && j == 0) {
        float acc = fcb[0];
        #pragma unroll
        for (int k = 0; k < H_; ++k) acc = fmaf(fcW[k], h1r[k], acc);
        out[b] = acc;
    }
}

extern "C" void kernel_launch(void* const* d_in, const int* in_sizes, int n_in,
                              void* d_out, int out_size, void* d_ws, size_t ws_size,
                              hipStream_t stream) {
    const float* x    = (const float*)d_in[0];
    const float* Wih0 = (const float*)d_in[1];
    const float* Whh0 = (const float*)d_in[2];
    const float* bih0 = (const float*)d_in[3];
    const float* bhh0 = (const float*)d_in[4];
    const float* Wih1 = (const float*)d_in[5];
    const float* Whh1 = (const float*)d_in[6];
    const float* bih1 = (const float*)d_in[7];
    const float* bhh1 = (const float*)d_in[8];
    const float* fcW  = (const float*)d_in[9];
    const float* fcb  = (const float*)d_in[10];
    float* out = (float*)d_out;

    const int grid = (B_ + GPB - 1) / GPB;   // 1366 blocks x 4 waves
    lstm2_fc_kernel<<<dim3(grid), dim3(256), 0, stream>>>(
        x, Wih0, Whh0, bih0, bhh0, Wih1, Whh1, bih1, bhh1, fcW, fcb, out);
}